// Round 1
// baseline (345463.403 us; speedup 1.0000x reference)
//
#include <hip/hip_runtime.h>
#include <hip/hip_bf16.h>
#include <math.h>

// Problem constants
#define T_STEPS 8192
#define HDIM    1024
#define GW      128     // workgroups in each scan kernel (1 per CU, all co-resident)

// Workspace layout (bytes)
#define OFF_REV   ((size_t)0)                         // 8192*64*4   = 2 MB
#define OFF_X1    ((size_t)2097152)                   // 8192*512*4  = 16 MB
#define OFF_B     ((size_t)18874368)                  // x2 then hs: 8192*1024*4 = 32 MB
#define OFF_C     ((size_t)52428800)                  // xp then y1: 8192*3072*4 = 96 MB
#define OFF_HBUF  ((size_t)153092096)                 // 2*1024*4
#define OFF_FLG   ((size_t)153100288)                 // 2*128*4
#define WS_NEEDED ((size_t)153101312)

__device__ inline float dot4f(float4 a, float4 b) {
    return a.x*b.x + a.y*b.y + a.z*b.z + a.w*b.w;
}
__device__ inline float sigmf(float x) { return 1.0f / (1.0f + expf(-x)); }

// ---------------------------------------------------------------------------
// build rev: rev[t][0:32]=weather[T-1-t], rev[t][32:64]=infect[T-1-t]
// ---------------------------------------------------------------------------
__global__ void build_rev(const float* __restrict__ wea, const float* __restrict__ inf,
                          float* __restrict__ rev) {
    int idx = blockIdx.x * blockDim.x + threadIdx.x;   // over T*64
    if (idx >= T_STEPS * 64) return;
    int t = idx >> 6, c = idx & 63;
    int ts = T_STEPS - 1 - t;
    rev[idx] = (c < 32) ? wea[ts * 32 + c] : inf[ts * 32 + (c - 32)];
}

// ---------------------------------------------------------------------------
// Tiled f32 GEMM: C[M,N] = act(A[M,K] @ W[N,K]^T + bias[N]); BM=BN=64, BK=32
// ---------------------------------------------------------------------------
__global__ __launch_bounds__(256) void gemm_bias_act(
    const float* __restrict__ A, const float* __restrict__ W,
    const float* __restrict__ bias, float* __restrict__ C,
    int M, int N, int K, int relu)
{
    __shared__ float As[32][68];
    __shared__ float Ws[32][68];
    const int tid = threadIdx.x;
    const int tx = tid & 15, ty = tid >> 4;
    const int bm = blockIdx.y, bn = blockIdx.x;
    const float* Ab = A + (size_t)bm * 64 * K;
    const float* Wb = W + (size_t)bn * 64 * K;
    float acc[4][4] = {};

    for (int k0 = 0; k0 < K; k0 += 32) {
#pragma unroll
        for (int q = 0; q < 2; ++q) {
            int idx = tid * 2 + q;           // 0..511
            int row = idx >> 3;              // 0..63
            int kc  = (idx & 7) << 2;        // 0..28
            float4 av = *(const float4*)(Ab + (size_t)row * K + k0 + kc);
            As[kc + 0][row] = av.x; As[kc + 1][row] = av.y;
            As[kc + 2][row] = av.z; As[kc + 3][row] = av.w;
            float4 wv = *(const float4*)(Wb + (size_t)row * K + k0 + kc);
            Ws[kc + 0][row] = wv.x; Ws[kc + 1][row] = wv.y;
            Ws[kc + 2][row] = wv.z; Ws[kc + 3][row] = wv.w;
        }
        __syncthreads();
#pragma unroll
        for (int k = 0; k < 32; ++k) {
            float4 a = *(const float4*)&As[k][ty << 2];
            float4 b = *(const float4*)&Ws[k][tx << 2];
            acc[0][0] += a.x*b.x; acc[0][1] += a.x*b.y; acc[0][2] += a.x*b.z; acc[0][3] += a.x*b.w;
            acc[1][0] += a.y*b.x; acc[1][1] += a.y*b.y; acc[1][2] += a.y*b.z; acc[1][3] += a.y*b.w;
            acc[2][0] += a.z*b.x; acc[2][1] += a.z*b.y; acc[2][2] += a.z*b.z; acc[2][3] += a.z*b.w;
            acc[3][0] += a.w*b.x; acc[3][1] += a.w*b.y; acc[3][2] += a.w*b.z; acc[3][3] += a.w*b.w;
        }
        __syncthreads();
    }

    int m0 = bm * 64 + (ty << 2), n0 = bn * 64 + (tx << 2);
    float4 bv = *(const float4*)(bias + n0);
#pragma unroll
    for (int r = 0; r < 4; ++r) {
        float4 o;
        o.x = acc[r][0] + bv.x; o.y = acc[r][1] + bv.y;
        o.z = acc[r][2] + bv.z; o.w = acc[r][3] + bv.w;
        if (relu) {
            o.x = fmaxf(o.x, 0.f); o.y = fmaxf(o.y, 0.f);
            o.z = fmaxf(o.z, 0.f); o.w = fmaxf(o.w, 0.f);
        }
        *(float4*)(C + (size_t)(m0 + r) * N + n0) = o;
    }
}

// ---------------------------------------------------------------------------
// Distributed grid barrier: monotonic per-WG flags, per-thread spin.
// ---------------------------------------------------------------------------
__device__ inline void grid_bar(unsigned* flags, int g, int tid, unsigned target) {
    __threadfence();               // make this WG's h stores device-visible
    __syncthreads();               // all waves' stores+fences done
    if (tid == 0)
        __hip_atomic_store(&flags[g], target, __ATOMIC_RELEASE, __HIP_MEMORY_SCOPE_AGENT);
    if (tid < GW) {
        while (__hip_atomic_load(&flags[tid], __ATOMIC_RELAXED, __HIP_MEMORY_SCOPE_AGENT) < target)
            __builtin_amdgcn_s_sleep(1);
    }
    __syncthreads();
    __threadfence();               // acquire: subsequent h loads see remote writes
}

// ---------------------------------------------------------------------------
// GRU scan. G=128 WGs x 256 thr. WG g owns h-outputs [g*8, g*8+8).
// Wave w owns 2 outputs; 6 rows of whh held in VGPRs (96 f32/lane).
// ---------------------------------------------------------------------------
__global__ __launch_bounds__(256, 1) void gru_scan(
    const float* __restrict__ whh,   // 3072x1024
    const float* __restrict__ bhh,   // 3072
    const float* __restrict__ xp,    // 8192x3072 (includes bih)
    float* __restrict__ hbuf,        // 2x1024 (hbuf[0] preloaded with h_init)
    float* __restrict__ hs,          // 8192x1024; we write hs[0]=h_enc at the end
    unsigned* flags)
{
    __shared__ float h_sh[HDIM];
    const int g = blockIdx.x, tid = threadIdx.x;
    const int w = tid >> 6, l = tid & 63;
    const int iA = g * 8 + w * 2, iB = iA + 1;
    const int rows[6] = { iA, HDIM + iA, 2*HDIM + iA, iB, HDIM + iB, 2*HDIM + iB };

    // weights -> VGPRs: lane l holds w[row][256j + 4l + c]
    float4 Wf[6][4];
#pragma unroll
    for (int r = 0; r < 6; ++r) {
        const float* wr = whh + (size_t)rows[r] * HDIM + 4 * l;
#pragma unroll
        for (int j = 0; j < 4; ++j) Wf[r][j] = *(const float4*)(wr + 256 * j);
    }
    float bh[6];
#pragma unroll
    for (int r = 0; r < 6; ++r) bh[r] = bhh[rows[r]];

    // prefetch xp for t=0 (lane 0 of each wave only)
    float xpv[6];
    if (l == 0) {
#pragma unroll
        for (int r = 0; r < 6; ++r) xpv[r] = xp[rows[r]];
    }

    for (int t = 0; t < T_STEPS; ++t) {
        // stage h into LDS
        const float* hsrc = hbuf + (size_t)(t & 1) * HDIM;
        float4 hv = *(const float4*)(hsrc + 4 * tid);
        *(float4*)&h_sh[4 * tid] = hv;
        __syncthreads();

        float4 h4[4];
#pragma unroll
        for (int j = 0; j < 4; ++j) h4[j] = *(const float4*)&h_sh[256 * j + 4 * l];

        float red[6];
#pragma unroll
        for (int r = 0; r < 6; ++r) {
            float v = dot4f(Wf[r][0], h4[0]) + dot4f(Wf[r][1], h4[1])
                    + dot4f(Wf[r][2], h4[2]) + dot4f(Wf[r][3], h4[3]);
#pragma unroll
            for (int off = 32; off > 0; off >>= 1) v += __shfl_xor(v, off, 64);
            red[r] = v;
        }

        if (l == 0) {
            float* hnext = hbuf + (size_t)((t + 1) & 1) * HDIM;
            // output iA
            float hhr = red[0] + bh[0], hhz = red[1] + bh[1], hhn = red[2] + bh[2];
            float r_ = sigmf(xpv[0] + hhr);
            float z_ = sigmf(xpv[1] + hhz);
            float n_ = tanhf(xpv[2] + r_ * hhn);
            float hA = (1.f - z_) * n_ + z_ * h_sh[iA];
            // output iB
            float hhr2 = red[3] + bh[3], hhz2 = red[4] + bh[4], hhn2 = red[5] + bh[5];
            float r2 = sigmf(xpv[3] + hhr2);
            float z2 = sigmf(xpv[4] + hhz2);
            float n2 = tanhf(xpv[5] + r2 * hhn2);
            float hB = (1.f - z2) * n2 + z2 * h_sh[iB];
            hnext[iA] = hA;
            hnext[iB] = hB;
            if (t == T_STEPS - 1) { hs[iA] = hA; hs[iB] = hB; }
            // prefetch next xp (hidden behind the barrier)
            if (t + 1 < T_STEPS) {
                const float* xq = xp + (size_t)(t + 1) * (3 * HDIM);
#pragma unroll
                for (int r = 0; r < 6; ++r) xpv[r] = xq[rows[r]];
            }
        }
        grid_bar(flags, g, tid, (unsigned)(t + 1));
    }
}

// ---------------------------------------------------------------------------
// LSTM-like decoder scan. h_new = o*tanh(i*g), rows {i, 2H+i, 3H+i} only
// (forget-gate rows [H,2H) are dead in the reference).
// ---------------------------------------------------------------------------
__global__ __launch_bounds__(256, 1) void lstm_scan(
    const float* __restrict__ wih,   // 4096x1024
    const float* __restrict__ bih,   // 4096
    const float* __restrict__ bhh,   // 4096
    float* __restrict__ hbuf,        // hbuf[0] holds h_enc at entry
    float* __restrict__ hs,          // 8192x1024; write hs[1..T-1]
    unsigned* flags)
{
    __shared__ float h_sh[HDIM];
    const int g = blockIdx.x, tid = threadIdx.x;
    const int w = tid >> 6, l = tid & 63;
    const int iA = g * 8 + w * 2, iB = iA + 1;
    const int rows[6] = { iA, 2*HDIM + iA, 3*HDIM + iA, iB, 2*HDIM + iB, 3*HDIM + iB };

    float4 Wf[6][4];
#pragma unroll
    for (int r = 0; r < 6; ++r) {
        const float* wr = wih + (size_t)rows[r] * HDIM + 4 * l;
#pragma unroll
        for (int j = 0; j < 4; ++j) Wf[r][j] = *(const float4*)(wr + 256 * j);
    }
    float bs[6];
#pragma unroll
    for (int r = 0; r < 6; ++r) bs[r] = bih[rows[r]] + bhh[rows[r]];

    for (int s = 1; s < T_STEPS; ++s) {
        const float* hsrc = hbuf + (size_t)((s + 1) & 1) * HDIM;
        float4 hv = *(const float4*)(hsrc + 4 * tid);
        *(float4*)&h_sh[4 * tid] = hv;
        __syncthreads();

        float4 h4[4];
#pragma unroll
        for (int j = 0; j < 4; ++j) h4[j] = *(const float4*)&h_sh[256 * j + 4 * l];

        float red[6];
#pragma unroll
        for (int r = 0; r < 6; ++r) {
            float v = dot4f(Wf[r][0], h4[0]) + dot4f(Wf[r][1], h4[1])
                    + dot4f(Wf[r][2], h4[2]) + dot4f(Wf[r][3], h4[3]);
#pragma unroll
            for (int off = 32; off > 0; off >>= 1) v += __shfl_xor(v, off, 64);
            red[r] = v;
        }

        if (l == 0) {
            float* hnext = hbuf + (size_t)(s & 1) * HDIM;
            float i1 = sigmf(red[0] + bs[0]);
            float g1 = tanhf(red[1] + bs[1]);
            float o1 = sigmf(red[2] + bs[2]);
            float hA = o1 * tanhf(i1 * g1);
            float i2 = sigmf(red[3] + bs[3]);
            float g2 = tanhf(red[4] + bs[4]);
            float o2 = sigmf(red[5] + bs[5]);
            float hB = o2 * tanhf(i2 * g2);
            hnext[iA] = hA; hnext[iB] = hB;
            hs[(size_t)s * HDIM + iA] = hA;
            hs[(size_t)s * HDIM + iB] = hB;
        }
        grid_bar(flags, g, tid, (unsigned)s);
    }
}

// ---------------------------------------------------------------------------
// Final tiny GEMM: out[t][0:8] = y1[t] @ dec_w2^T + dec_b2, one wave per t
// ---------------------------------------------------------------------------
__global__ __launch_bounds__(256) void dec2_kernel(
    const float* __restrict__ y1,    // 8192x512
    const float* __restrict__ w2,    // 8x512
    const float* __restrict__ b2,    // 8
    float* __restrict__ out)         // 8192x8
{
    const int w = threadIdx.x >> 6, l = threadIdx.x & 63;
    const int t = blockIdx.x * 4 + w;
    const float* yr = y1 + (size_t)t * 512;
    float yv[8];
#pragma unroll
    for (int j = 0; j < 8; ++j) yv[j] = yr[l + 64 * j];
    float o[8];
#pragma unroll
    for (int n = 0; n < 8; ++n) {
        const float* wr = w2 + n * 512;
        float s = 0.f;
#pragma unroll
        for (int j = 0; j < 8; ++j) s += yv[j] * wr[l + 64 * j];
#pragma unroll
        for (int off = 32; off > 0; off >>= 1) s += __shfl_xor(s, off, 64);
        o[n] = s;
    }
    if (l == 0) {
#pragma unroll
        for (int n = 0; n < 8; ++n) out[(size_t)t * 8 + n] = o[n] + b2[n];
    }
}

// ---------------------------------------------------------------------------
extern "C" void kernel_launch(void* const* d_in, const int* in_sizes, int n_in,
                              void* d_out, int out_size, void* d_ws, size_t ws_size,
                              hipStream_t stream)
{
    const float* wea      = (const float*)d_in[0];
    const float* inf      = (const float*)d_in[1];
    // d_in[2] time_window: unused by the reference
    const float* h_init   = (const float*)d_in[3];
    const float* enc_w1   = (const float*)d_in[4];
    const float* enc_b1   = (const float*)d_in[5];
    const float* enc_w2   = (const float*)d_in[6];
    const float* enc_b2   = (const float*)d_in[7];
    const float* gru_wih  = (const float*)d_in[8];
    const float* gru_whh  = (const float*)d_in[9];
    const float* gru_bih  = (const float*)d_in[10];
    const float* gru_bhh  = (const float*)d_in[11];
    const float* lstm_wih = (const float*)d_in[12];
    const float* lstm_bih = (const float*)d_in[13];
    const float* lstm_bhh = (const float*)d_in[14];
    const float* dec_w1   = (const float*)d_in[15];
    const float* dec_b1   = (const float*)d_in[16];
    const float* dec_w2   = (const float*)d_in[17];
    const float* dec_b2   = (const float*)d_in[18];

    if (ws_size < WS_NEEDED) return;  // workspace too small; avoid corruption

    char* ws = (char*)d_ws;
    float*    rev   = (float*)(ws + OFF_REV);
    float*    x1    = (float*)(ws + OFF_X1);
    float*    x2    = (float*)(ws + OFF_B);    // later reused as hs
    float*    hs    = (float*)(ws + OFF_B);
    float*    xp    = (float*)(ws + OFF_C);    // later reused as y1
    float*    y1    = (float*)(ws + OFF_C);
    float*    hbuf  = (float*)(ws + OFF_HBUF);
    unsigned* flags = (unsigned*)(ws + OFF_FLG);

    // init: flags=0, hbuf[0]=h_init
    hipMemsetAsync(flags, 0, 2 * GW * sizeof(unsigned), stream);
    hipMemcpyAsync(hbuf, h_init, HDIM * sizeof(float), hipMemcpyDeviceToDevice, stream);

    build_rev<<<(T_STEPS * 64) / 256, 256, 0, stream>>>(wea, inf, rev);

    // encoder
    gemm_bias_act<<<dim3(8, 128), 256, 0, stream>>>(rev, enc_w1, enc_b1, x1,
                                                    T_STEPS, 512, 64, 1);
    gemm_bias_act<<<dim3(16, 128), 256, 0, stream>>>(x1, enc_w2, enc_b2, x2,
                                                     T_STEPS, 1024, 512, 1);
    // GRU input projection xp = x2 @ gru_wih^T + gru_bih
    gemm_bias_act<<<dim3(48, 128), 256, 0, stream>>>(x2, gru_wih, gru_bih, xp,
                                                     T_STEPS, 3 * HDIM, HDIM, 0);
    // sequential scans
    gru_scan<<<GW, 256, 0, stream>>>(gru_whh, gru_bhh, xp, hbuf, hs, flags);
    lstm_scan<<<GW, 256, 0, stream>>>(lstm_wih, lstm_bih, lstm_bhh, hbuf, hs, flags + GW);

    // decoder
    gemm_bias_act<<<dim3(8, 128), 256, 0, stream>>>(hs, dec_w1, dec_b1, y1,
                                                    T_STEPS, 512, HDIM, 1);
    dec2_kernel<<<T_STEPS / 4, 256, 0, stream>>>(y1, dec_w2, dec_b2, (float*)d_out);
}

// Round 2
// 48972.577 us; speedup vs baseline: 7.0542x; 7.0542x over previous
//
#include <hip/hip_runtime.h>
#include <hip/hip_bf16.h>
#include <math.h>

// Problem constants
#define T_STEPS 8192
#define HDIM    1024
#define GW      128     // workgroups per scan kernel (1 per CU, all co-resident)
#define NSLOT   512     // one slot per wave: 2 h-values + tag

// Workspace layout (bytes)
#define OFF_REV   ((size_t)0)                         // 8192*64*4   = 2 MB
#define OFF_X1    ((size_t)2097152)                   // 8192*512*4  = 16 MB (reused as slots after gemm2)
#define OFF_B     ((size_t)18874368)                  // x2 then hs: 8192*1024*4 = 32 MB
#define OFF_C     ((size_t)52428800)                  // xp then y1: 8192*3072*4 = 96 MB
#define WS_NEEDED ((size_t)153092096)

typedef float f4 __attribute__((ext_vector_type(4)));

__device__ inline float sigm(float x)   { return 1.0f / (1.0f + __expf(-x)); }
__device__ inline float tanh_f(float x) { float e = __expf(2.0f * x); return 1.0f - 2.0f / (e + 1.0f); }

// Coherent (L1+L2-bypassing) 16B load/store: tag travels with data in one transaction.
__device__ inline f4 load_cohr(const f4* p) {
    f4 v;
    asm volatile("global_load_dwordx4 %0, %1, off sc0 sc1\n\ts_waitcnt vmcnt(0)"
                 : "=v"(v) : "v"(p) : "memory");
    return v;
}
__device__ inline void store_cohr(f4* p, f4 v) {
    asm volatile("global_store_dwordx4 %0, %1, off sc0 sc1"
                 :: "v"(p), "v"(v) : "memory");
}
__device__ inline f4 poll_slot(const f4* p, unsigned want) {
    f4 v = load_cohr(p);
    while (__float_as_uint(v.w) != want) {
        __builtin_amdgcn_s_sleep(1);
        v = load_cohr(p);
    }
    return v;
}

// ---------------------------------------------------------------------------
// build rev: rev[t][0:32]=weather[T-1-t], rev[t][32:64]=infect[T-1-t]
// ---------------------------------------------------------------------------
__global__ void build_rev(const float* __restrict__ wea, const float* __restrict__ inf,
                          float* __restrict__ rev) {
    int idx = blockIdx.x * blockDim.x + threadIdx.x;   // over T*64
    if (idx >= T_STEPS * 64) return;
    int t = idx >> 6, c = idx & 63;
    int ts = T_STEPS - 1 - t;
    rev[idx] = (c < 32) ? wea[ts * 32 + c] : inf[ts * 32 + (c - 32)];
}

// ---------------------------------------------------------------------------
// seed slots with h_init, tag 0 (coherent stores -> visible to poll loads)
// ---------------------------------------------------------------------------
__global__ void seed_slots(const float* __restrict__ h0, f4* __restrict__ slots) {
    int i = blockIdx.x * blockDim.x + threadIdx.x;
    if (i < NSLOT) {
        f4 v;
        v.x = h0[2 * i]; v.y = h0[2 * i + 1]; v.z = 0.0f;
        v.w = __uint_as_float(0u);
        store_cohr(&slots[i], v);
    }
}

// ---------------------------------------------------------------------------
// Tiled f32 GEMM: C[M,N] = act(A[M,K] @ W[N,K]^T + bias[N]); BM=BN=64, BK=32
// ---------------------------------------------------------------------------
__global__ __launch_bounds__(256) void gemm_bias_act(
    const float* __restrict__ A, const float* __restrict__ W,
    const float* __restrict__ bias, float* __restrict__ C,
    int M, int N, int K, int relu)
{
    __shared__ float As[32][68];
    __shared__ float Ws[32][68];
    const int tid = threadIdx.x;
    const int tx = tid & 15, ty = tid >> 4;
    const int bm = blockIdx.y, bn = blockIdx.x;
    const float* Ab = A + (size_t)bm * 64 * K;
    const float* Wb = W + (size_t)bn * 64 * K;
    float acc[4][4] = {};

    for (int k0 = 0; k0 < K; k0 += 32) {
#pragma unroll
        for (int q = 0; q < 2; ++q) {
            int idx = tid * 2 + q;           // 0..511
            int row = idx >> 3;              // 0..63
            int kc  = (idx & 7) << 2;        // 0..28
            float4 av = *(const float4*)(Ab + (size_t)row * K + k0 + kc);
            As[kc + 0][row] = av.x; As[kc + 1][row] = av.y;
            As[kc + 2][row] = av.z; As[kc + 3][row] = av.w;
            float4 wv = *(const float4*)(Wb + (size_t)row * K + k0 + kc);
            Ws[kc + 0][row] = wv.x; Ws[kc + 1][row] = wv.y;
            Ws[kc + 2][row] = wv.z; Ws[kc + 3][row] = wv.w;
        }
        __syncthreads();
#pragma unroll
        for (int k = 0; k < 32; ++k) {
            float4 a = *(const float4*)&As[k][ty << 2];
            float4 b = *(const float4*)&Ws[k][tx << 2];
            acc[0][0] += a.x*b.x; acc[0][1] += a.x*b.y; acc[0][2] += a.x*b.z; acc[0][3] += a.x*b.w;
            acc[1][0] += a.y*b.x; acc[1][1] += a.y*b.y; acc[1][2] += a.y*b.z; acc[1][3] += a.y*b.w;
            acc[2][0] += a.z*b.x; acc[2][1] += a.z*b.y; acc[2][2] += a.z*b.z; acc[2][3] += a.z*b.w;
            acc[3][0] += a.w*b.x; acc[3][1] += a.w*b.y; acc[3][2] += a.w*b.z; acc[3][3] += a.w*b.w;
        }
        __syncthreads();
    }

    int m0 = bm * 64 + (ty << 2), n0 = bn * 64 + (tx << 2);
    float4 bv = *(const float4*)(bias + n0);
#pragma unroll
    for (int r = 0; r < 4; ++r) {
        float4 o;
        o.x = acc[r][0] + bv.x; o.y = acc[r][1] + bv.y;
        o.z = acc[r][2] + bv.z; o.w = acc[r][3] + bv.w;
        if (relu) {
            o.x = fmaxf(o.x, 0.f); o.y = fmaxf(o.y, 0.f);
            o.z = fmaxf(o.z, 0.f); o.w = fmaxf(o.w, 0.f);
        }
        *(float4*)(C + (size_t)(m0 + r) * N + n0) = o;
    }
}

// ---------------------------------------------------------------------------
// GRU scan. 128 WGs x 256 thr; wave wv=g*4+w owns h[2wv],h[2wv+1].
// Weights pinned in VGPRs (asm touch). Tag-in-data slot protocol, no fences.
// Tags: read tag t from slots[t&1], publish tag t+1 into slots[(t+1)&1].
// ---------------------------------------------------------------------------
__global__ __launch_bounds__(256, 1) void gru_scan(
    const float* __restrict__ whh,   // 3072x1024
    const float* __restrict__ bhh,   // 3072
    const float* __restrict__ xp,    // 8192x3072 (includes bih)
    f4* __restrict__ slots,          // [2][NSLOT]
    float* __restrict__ hs)          // 8192x1024; hs[0]=h_enc written at end
{
    __shared__ float h_sh[2][HDIM];
    const int g = blockIdx.x, tid = threadIdx.x;
    const int w = tid >> 6, l = tid & 63;
    const int wv = g * 4 + w;
    const int iA = 2 * wv, iB = iA + 1;
    const int rows[6] = { iA, HDIM + iA, 2*HDIM + iA, iB, HDIM + iB, 2*HDIM + iB };

    // weights -> VGPRs: lane l holds w[row][256j + 4l .. +3]
    f4 Wf[6][4];
#pragma unroll
    for (int r = 0; r < 6; ++r) {
        const float* wr = whh + (size_t)rows[r] * HDIM + 4 * l;
#pragma unroll
        for (int j = 0; j < 4; ++j) Wf[r][j] = *(const f4*)(wr + 256 * j);
    }
#pragma unroll
    for (int r = 0; r < 6; ++r)
#pragma unroll
        for (int j = 0; j < 4; ++j)
            asm volatile("" : "+v"(Wf[r][j]));   // pin: opaque def, cannot remat

    // per-output constants on lanes 0 (output iA) and 1 (output iB)
    float b0 = 0.f, b1 = 0.f, b2 = 0.f;
    float xv0 = 0.f, xv1 = 0.f, xv2 = 0.f;
    int xrow = (l == 0) ? iA : iB;
    if (l < 2) {
        b0 = bhh[xrow]; b1 = bhh[HDIM + xrow]; b2 = bhh[2*HDIM + xrow];
        xv0 = xp[xrow]; xv1 = xp[HDIM + xrow]; xv2 = xp[2*HDIM + xrow];
    }

    for (int t = 0; t < T_STEPS; ++t) {
        const int buf = t & 1;
        // poll the two slots this thread stages (h[4tid..4tid+3])
        f4 sa = poll_slot(slots + (size_t)buf * NSLOT + 2 * tid,     (unsigned)t);
        f4 sb = poll_slot(slots + (size_t)buf * NSLOT + 2 * tid + 1, (unsigned)t);
        h_sh[buf][4*tid + 0] = sa.x; h_sh[buf][4*tid + 1] = sa.y;
        h_sh[buf][4*tid + 2] = sb.x; h_sh[buf][4*tid + 3] = sb.y;
        __syncthreads();

        f4 h4[4];
#pragma unroll
        for (int j = 0; j < 4; ++j) h4[j] = *(const f4*)&h_sh[buf][256*j + 4*l];

        float red[6];
#pragma unroll
        for (int r = 0; r < 6; ++r) {
            f4 p = Wf[r][0]*h4[0] + Wf[r][1]*h4[1] + Wf[r][2]*h4[2] + Wf[r][3]*h4[3];
            float v = p.x + p.y + p.z + p.w;
#pragma unroll
            for (int off = 32; off > 0; off >>= 1) v += __shfl_xor(v, off, 64);
            red[r] = v;
        }

        // gate math: lane0 -> output iA, lane1 -> output iB
        float hn = 0.f;
        if (l < 2) {
            float rd0 = (l == 0) ? red[0] : red[3];
            float rd1 = (l == 0) ? red[1] : red[4];
            float rd2 = (l == 0) ? red[2] : red[5];
            float hh_r = rd0 + b0, hh_z = rd1 + b1, hh_n = rd2 + b2;
            float r_ = sigm(xv0 + hh_r);
            float z_ = sigm(xv1 + hh_z);
            float n_ = tanh_f(xv2 + r_ * hh_n);
            float hp = h_sh[buf][xrow];
            hn = (1.0f - z_) * n_ + z_ * hp;
        }
        float hBv = __shfl(hn, 1, 64);
        if (l == 0) {
            unsigned pub = (unsigned)(t + 1);
            f4 s; s.x = hn; s.y = hBv; s.z = 0.0f; s.w = __uint_as_float(pub);
            store_cohr(slots + (size_t)(pub & 1) * NSLOT + wv, s);
            if (t == T_STEPS - 1) { hs[iA] = hn; hs[iB] = hBv; }
        }
        // prefetch next xp (off critical path; lands during next poll)
        if (l < 2 && t + 1 < T_STEPS) {
            const float* xq = xp + (size_t)(t + 1) * (3 * HDIM);
            xv0 = xq[xrow]; xv1 = xq[HDIM + xrow]; xv2 = xq[2*HDIM + xrow];
        }
    }
}

// ---------------------------------------------------------------------------
// LSTM-like decoder scan: h_new = o*tanh(i*g); forget rows [H,2H) are dead.
// Continues the tag sequence: reads tag 8191+s, publishes 8192+s.
// ---------------------------------------------------------------------------
__global__ __launch_bounds__(256, 1) void lstm_scan(
    const float* __restrict__ wih,   // 4096x1024
    const float* __restrict__ bih,   // 4096
    const float* __restrict__ bhh,   // 4096
    f4* __restrict__ slots,          // [2][NSLOT]
    float* __restrict__ hs)          // 8192x1024; write hs[1..T-1]
{
    __shared__ float h_sh[2][HDIM];
    const int g = blockIdx.x, tid = threadIdx.x;
    const int w = tid >> 6, l = tid & 63;
    const int wv = g * 4 + w;
    const int iA = 2 * wv, iB = iA + 1;
    const int rows[6] = { iA, 2*HDIM + iA, 3*HDIM + iA, iB, 2*HDIM + iB, 3*HDIM + iB };

    f4 Wf[6][4];
#pragma unroll
    for (int r = 0; r < 6; ++r) {
        const float* wr = wih + (size_t)rows[r] * HDIM + 4 * l;
#pragma unroll
        for (int j = 0; j < 4; ++j) Wf[r][j] = *(const f4*)(wr + 256 * j);
    }
#pragma unroll
    for (int r = 0; r < 6; ++r)
#pragma unroll
        for (int j = 0; j < 4; ++j)
            asm volatile("" : "+v"(Wf[r][j]));

    float b0 = 0.f, b1 = 0.f, b2 = 0.f;
    int xrow = (l == 0) ? iA : iB;
    if (l < 2) {
        b0 = bih[xrow]          + bhh[xrow];
        b1 = bih[2*HDIM + xrow] + bhh[2*HDIM + xrow];
        b2 = bih[3*HDIM + xrow] + bhh[3*HDIM + xrow];
    }

    for (int s = 1; s < T_STEPS; ++s) {
        const unsigned want = (unsigned)(8191 + s);
        const unsigned pub  = (unsigned)(8192 + s);
        const int buf = (int)(want & 1);
        f4 sa = poll_slot(slots + (size_t)buf * NSLOT + 2 * tid,     want);
        f4 sb = poll_slot(slots + (size_t)buf * NSLOT + 2 * tid + 1, want);
        h_sh[buf][4*tid + 0] = sa.x; h_sh[buf][4*tid + 1] = sa.y;
        h_sh[buf][4*tid + 2] = sb.x; h_sh[buf][4*tid + 3] = sb.y;
        __syncthreads();

        f4 h4[4];
#pragma unroll
        for (int j = 0; j < 4; ++j) h4[j] = *(const f4*)&h_sh[buf][256*j + 4*l];

        float red[6];
#pragma unroll
        for (int r = 0; r < 6; ++r) {
            f4 p = Wf[r][0]*h4[0] + Wf[r][1]*h4[1] + Wf[r][2]*h4[2] + Wf[r][3]*h4[3];
            float v = p.x + p.y + p.z + p.w;
#pragma unroll
            for (int off = 32; off > 0; off >>= 1) v += __shfl_xor(v, off, 64);
            red[r] = v;
        }

        float hn = 0.f;
        if (l < 2) {
            float rd0 = (l == 0) ? red[0] : red[3];
            float rd1 = (l == 0) ? red[1] : red[4];
            float rd2 = (l == 0) ? red[2] : red[5];
            float i_ = sigm(rd0 + b0);
            float g_ = tanh_f(rd1 + b1);
            float o_ = sigm(rd2 + b2);
            hn = o_ * tanh_f(i_ * g_);
        }
        float hBv = __shfl(hn, 1, 64);
        if (l == 0) {
            f4 sv; sv.x = hn; sv.y = hBv; sv.z = 0.0f; sv.w = __uint_as_float(pub);
            store_cohr(slots + (size_t)(pub & 1) * NSLOT + wv, sv);
            hs[(size_t)s * HDIM + iA] = hn;
            hs[(size_t)s * HDIM + iB] = hBv;
        }
    }
}

// ---------------------------------------------------------------------------
// Final tiny GEMM: out[t][0:8] = y1[t] @ dec_w2^T + dec_b2, one wave per t
// ---------------------------------------------------------------------------
__global__ __launch_bounds__(256) void dec2_kernel(
    const float* __restrict__ y1,    // 8192x512
    const float* __restrict__ w2,    // 8x512
    const float* __restrict__ b2,    // 8
    float* __restrict__ out)         // 8192x8
{
    const int w = threadIdx.x >> 6, l = threadIdx.x & 63;
    const int t = blockIdx.x * 4 + w;
    const float* yr = y1 + (size_t)t * 512;
    float yv[8];
#pragma unroll
    for (int j = 0; j < 8; ++j) yv[j] = yr[l + 64 * j];
    float o[8];
#pragma unroll
    for (int n = 0; n < 8; ++n) {
        const float* wr = w2 + n * 512;
        float s = 0.f;
#pragma unroll
        for (int j = 0; j < 8; ++j) s += yv[j] * wr[l + 64 * j];
#pragma unroll
        for (int off = 32; off > 0; off >>= 1) s += __shfl_xor(s, off, 64);
        o[n] = s;
    }
    if (l == 0) {
#pragma unroll
        for (int n = 0; n < 8; ++n) out[(size_t)t * 8 + n] = o[n] + b2[n];
    }
}

// ---------------------------------------------------------------------------
extern "C" void kernel_launch(void* const* d_in, const int* in_sizes, int n_in,
                              void* d_out, int out_size, void* d_ws, size_t ws_size,
                              hipStream_t stream)
{
    const float* wea      = (const float*)d_in[0];
    const float* inf      = (const float*)d_in[1];
    const float* h_init   = (const float*)d_in[3];
    const float* enc_w1   = (const float*)d_in[4];
    const float* enc_b1   = (const float*)d_in[5];
    const float* enc_w2   = (const float*)d_in[6];
    const float* enc_b2   = (const float*)d_in[7];
    const float* gru_wih  = (const float*)d_in[8];
    const float* gru_whh  = (const float*)d_in[9];
    const float* gru_bih  = (const float*)d_in[10];
    const float* gru_bhh  = (const float*)d_in[11];
    const float* lstm_wih = (const float*)d_in[12];
    const float* lstm_bih = (const float*)d_in[13];
    const float* lstm_bhh = (const float*)d_in[14];
    const float* dec_w1   = (const float*)d_in[15];
    const float* dec_b1   = (const float*)d_in[16];
    const float* dec_w2   = (const float*)d_in[17];
    const float* dec_b2   = (const float*)d_in[18];

    if (ws_size < WS_NEEDED) return;

    char* ws = (char*)d_ws;
    float* rev   = (float*)(ws + OFF_REV);
    float* x1    = (float*)(ws + OFF_X1);
    float* x2    = (float*)(ws + OFF_B);    // later reused as hs
    float* hs    = (float*)(ws + OFF_B);
    float* xp    = (float*)(ws + OFF_C);    // later reused as y1
    float* y1    = (float*)(ws + OFF_C);
    f4*    slots = (f4*)(ws + OFF_X1);      // x1 is dead after gemm2; 16 KB

    build_rev<<<(T_STEPS * 64) / 256, 256, 0, stream>>>(wea, inf, rev);

    // encoder
    gemm_bias_act<<<dim3(8, 128), 256, 0, stream>>>(rev, enc_w1, enc_b1, x1,
                                                    T_STEPS, 512, 64, 1);
    gemm_bias_act<<<dim3(16, 128), 256, 0, stream>>>(x1, enc_w2, enc_b2, x2,
                                                     T_STEPS, 1024, 512, 1);
    // GRU input projection xp = x2 @ gru_wih^T + gru_bih
    gemm_bias_act<<<dim3(48, 128), 256, 0, stream>>>(x2, gru_wih, gru_bih, xp,
                                                     T_STEPS, 3 * HDIM, HDIM, 0);
    // seed slot buffer (x1 region is now dead) and run the scans
    seed_slots<<<2, 256, 0, stream>>>(h_init, slots);
    gru_scan<<<GW, 256, 0, stream>>>(gru_whh, gru_bhh, xp, slots, hs);
    lstm_scan<<<GW, 256, 0, stream>>>(lstm_wih, lstm_bih, lstm_bhh, slots, hs);

    // decoder
    gemm_bias_act<<<dim3(8, 128), 256, 0, stream>>>(hs, dec_w1, dec_b1, y1,
                                                    T_STEPS, 512, HDIM, 1);
    dec2_kernel<<<T_STEPS / 4, 256, 0, stream>>>(y1, dec_w2, dec_b2, (float*)d_out);
}